// Round 4
// baseline (74.592 us; speedup 1.0000x reference)
//
#include <hip/hip_runtime.h>

// NURBS surface evaluation, MI355X — single fused kernel, fast-rcp divides.
// Inputs:  cp (256,256,3) f32, kvx (1,260) f32, kvy (1,260) f32
// Output:  (1,1024,1024,3) f32
//
// Every block independently:
//  1. normalizes both knot vectors (clamp<0 -> 1e-4, blocked shfl-scan cumsum,
//     affine normalize) into LDS. Reassociation + rcp perturb knots ~1e-7 rel;
//     output perturbation ~1e-6, far under the 6.3e-2 threshold.
//  2. Cox-de-Boor basis + wrapped control indices for its one e (block-uniform)
//     and 256 f values (one per thread). All divides via v_rcp_f32 (1 ulp) —
//     IEEE div_scale/div_fmas/div_fixup sequences were ~half the kernel VALU.
//  3. 4x4 weighted blend from the 768KB L2-resident control-point table.
//  4. repack through LDS, coalesced float4 store.

#define KLEN  260
#define NCTRL 256
#define OUTN  1024
#define DEG   3
#define EPSV  1e-5
#define CHUNK 5   // 52 lanes x 5 = 260 knots per wave

__device__ __forceinline__ float fast_rcp(float x) {
  return __builtin_amdgcn_rcpf(x);   // v_rcp_f32, ~1 ulp
}

__device__ __forceinline__ void basis_eval(const float* __restrict__ k,
                                           int idx, float* w, int* ci) {
  const double step = (1.0 - 2.0 * (double)EPSV) / (double)(OUTN - 1);
  const float u = (float)((double)EPSV + (double)idx * step);

  // searchsorted(k, u, side='right') - 1
  int lo = 0, hi = KLEN;
  while (lo < hi) {
    int mid = (lo + hi) >> 1;
    if (k[mid] <= u) lo = mid + 1; else hi = mid;
  }
  int span = lo - 1;
  if (u == k[NCTRL]) span = NCTRL - 1;

  // Wrap offsets are at most +/-3 and span in [0, 258]: one correction suffices.
  float left[DEG + 1], right[DEG + 1], cols[DEG + 1];
  cols[0] = 1.f;
  #pragma unroll
  for (int j = 1; j <= DEG; ++j) {
    int li = span + 1 - j; if (li < 0)     li += KLEN;
    int ri = span + j;     if (ri >= KLEN) ri -= KLEN;
    left[j]  = u - k[li];
    right[j] = k[ri] - u;
    float saved = 0.f;
    #pragma unroll
    for (int r = 0; r < j; ++r) {
      float temp = cols[r] * fast_rcp(right[r + 1] + left[j - r]);
      cols[r] = saved + right[r + 1] * temp;
      saved = left[j - r] * temp;
    }
    cols[j] = saved;
  }
  #pragma unroll
  for (int l = 0; l <= DEG; ++l) {
    w[l]  = cols[l];
    ci[l] = (span - DEG + l) & (NCTRL - 1);
  }
}

__global__ __launch_bounds__(256) void nurbs_fused(
    const float* __restrict__ cp,
    const float* __restrict__ kvx, const float* __restrict__ kvy,
    float* __restrict__ out) {
  __shared__ float kn[2][KLEN];
  __shared__ float sbuf[256 * 3];

  const int t    = threadIdx.x;
  const int wave = t >> 6;
  const int lane = t & 63;

  // ---- knot normalization: wave 0 -> x knots, wave 1 -> y knots ----
  if (wave < 2) {
    const float* kv = (wave == 0) ? kvx : kvy;
    float v[CHUNK];
    float lsum = 0.f;
    if (lane < 52) {
      #pragma unroll
      for (int j = 0; j < CHUNK; ++j) {
        float x = kv[lane * CHUNK + j];
        x = (x < 0.f) ? 1e-4f : x;
        v[j] = x;
        lsum += x;
      }
    } else {
      #pragma unroll
      for (int j = 0; j < CHUNK; ++j) v[j] = 0.f;
    }
    // inclusive shfl scan of per-lane sums (wave64)
    float s = lsum;
    #pragma unroll
    for (int d = 1; d < 64; d <<= 1) {
      float n = __shfl_up(s, d);
      if (lane >= d) s += n;
    }
    const float excl  = s - lsum;
    const float total = __shfl(s, 51);     // cumsum[KLEN-1]
    const float c0    = __shfl(v[0], 0);   // cumsum[0]
    const float inv_d = fast_rcp(total - c0);
    if (lane < 52) {
      float run = excl;
      #pragma unroll
      for (int j = 0; j < CHUNK; ++j) {
        run += v[j];
        kn[wave][lane * CHUNK + j] = (run - c0) * inv_d;
      }
    }
  }
  __syncthreads();

  const int bx    = blockIdx.x;
  const int e     = bx >> 2;
  const int fbase = (bx & 3) << 8;
  const int f     = fbase + t;

  float wE[4], wF[4];
  int   iE[4], iF[4];
  basis_eval(kn[0], e, wE, iE);   // block-uniform
  basis_eval(kn[1], f, wF, iF);   // per-thread

  float ax = 0.f, ay = 0.f, az = 0.f;
  #pragma unroll
  for (int l = 0; l < 4; ++l) {
    const float* rowp = cp + iE[l] * (NCTRL * 3);
    const float wl = wE[l];
    #pragma unroll
    for (int r = 0; r < 4; ++r) {
      const float w = wl * wF[r];
      const float* p = rowp + iF[r] * 3;
      ax += w * p[0];
      ay += w * p[1];
      az += w * p[2];
    }
  }

  // repack through LDS -> coalesced float4 stores (stride-3 LDS: odd, conflict-free)
  sbuf[t * 3 + 0] = ax;
  sbuf[t * 3 + 1] = ay;
  sbuf[t * 3 + 2] = az;
  __syncthreads();

  float4* ob = (float4*)(out + (size_t)(e * OUTN + fbase) * 3);
  if (t < 192) ob[t] = ((const float4*)sbuf)[t];
}

extern "C" void kernel_launch(void* const* d_in, const int* in_sizes, int n_in,
                              void* d_out, int out_size, void* d_ws, size_t ws_size,
                              hipStream_t stream) {
  (void)in_sizes; (void)n_in; (void)out_size; (void)d_ws; (void)ws_size;
  const float* cp  = (const float*)d_in[0];
  const float* kvx = (const float*)d_in[1];
  const float* kvy = (const float*)d_in[2];
  float* out = (float*)d_out;

  nurbs_fused<<<4096, 256, 0, stream>>>(cp, kvx, kvy, out);
}